// Round 2
// baseline (651.735 us; speedup 1.0000x reference)
//
#include <hip/hip_runtime.h>

#define TW 32
#define TH 32
#define SW 42          // TW + 10 halo
#define SH 42          // TH + 10 halo
#define SPITCH 44      // staged-tile pitch (multiple of 4 -> 16B-aligned float4)
#define HPITCH 36      // h-filtered pitch (mult of 4; 36 mod 32 = 4 bank shift)
#define BLOCK 256
#define IMG_W 768
#define IMG_H 768
#define IMG_B 32
#define GX_ (IMG_W / TW)
#define GY_ (IMG_H / TH)
#define NBLOCKS (GX_ * GY_ * IMG_B)   // 18432
#define NSLOTS 32
#define PER_SLOT (NBLOCKS / NSLOTS)   // 576

// Gaussian window sigma=1.5, ws=11, normalized; computed offline in f64 to
// match numpy's float64 window after f32 cast (<= 1-2 ulp).
#define W0 0.00102838f
#define W1 0.00759876f
#define W2 0.03600077f
#define W3 0.10936069f
#define W4 0.21300554f
#define W5 0.26601173f

__global__ __launch_bounds__(BLOCK, 3) void ssim_fused_kernel(
    const float* __restrict__ pred, const float* __restrict__ yin,
    float* __restrict__ out, void* __restrict__ ws)
{
    constexpr float GW[11] = {W0, W1, W2, W3, W4, W5, W4, W3, W2, W1, W0};

    __shared__ __align__(16) float sp[SH * SPITCH];
    __shared__ __align__(16) float sy[SH * SPITCH];
    __shared__ __align__(16) float Hb[5][SH][HPITCH];
    __shared__ float wsum[BLOCK / 64];
    __shared__ unsigned lastFlag;

    const int tid = threadIdx.x;
    const int x0 = blockIdx.x * TW;
    const int y0 = blockIdx.y * TH;
    const size_t base = (size_t)blockIdx.z * (size_t)(IMG_H * IMG_W);
    const float* pb = pred + base;
    const float* yb = yin + base;

    // ---- stage 42x42 halo'd tile ----
    const bool interior = (x0 >= 5) && (x0 + TW + 5 <= IMG_W) &&
                          (y0 >= 5) && (y0 + TH + 5 <= IMG_H);
    {
        int r = tid / SW;
        int c = tid - r * SW;
        if (interior) {
            const float* pb2 = pb + (size_t)(y0 - 5) * IMG_W + (x0 - 5);
            const float* yb2 = yb + (size_t)(y0 - 5) * IMG_W + (x0 - 5);
            for (int it = tid; it < SH * SW; it += BLOCK) {
                int o = r * IMG_W + c;
                sp[r * SPITCH + c] = pb2[o];
                sy[r * SPITCH + c] = yb2[o];
                c += 4; r += 6;                  // 256 = 6*42 + 4
                if (c >= SW) { c -= SW; ++r; }
            }
        } else {
            for (int it = tid; it < SH * SW; it += BLOCK) {
                int gx = x0 + c - 5;
                int gy = y0 + r - 5;
                float vp = 0.f, vy = 0.f;
                if (gx >= 0 && gx < IMG_W && gy >= 0 && gy < IMG_H) {
                    size_t o = (size_t)gy * IMG_W + gx;
                    vp = pb[o];
                    vy = yb[o];
                }
                sp[r * SPITCH + c] = vp;
                sy[r * SPITCH + c] = vy;
                c += 4; r += 6;
                if (c >= SW) { c -= SW; ++r; }
            }
        }
    }
    __syncthreads();

    // ---- horizontal pass: 42 rows x 8 col-groups (4 outputs each) ----
    for (int it = tid; it < SH * 8; it += BLOCK) {
        const int hr = it >> 3;
        const int c0 = (it & 7) << 2;
        const float* rp = &sp[hr * SPITCH + c0];
        const float* ry = &sy[hr * SPITCH + c0];
        float p[14], q[14];
        *(float4*)(p)      = *(const float4*)(rp);
        *(float4*)(p + 4)  = *(const float4*)(rp + 4);
        *(float4*)(p + 8)  = *(const float4*)(rp + 8);
        *(float2*)(p + 12) = *(const float2*)(rp + 12);
        *(float4*)(q)      = *(const float4*)(ry);
        *(float4*)(q + 4)  = *(const float4*)(ry + 4);
        *(float4*)(q + 8)  = *(const float4*)(ry + 8);
        *(float2*)(q + 12) = *(const float2*)(ry + 12);

        float pp[14], qq[14], pq[14];
        #pragma unroll
        for (int k = 0; k < 14; ++k) {
            pp[k] = p[k] * p[k];
            qq[k] = q[k] * q[k];
            pq[k] = p[k] * q[k];
        }

        float a[4][5];
        #pragma unroll
        for (int o = 0; o < 4; ++o)
            #pragma unroll
            for (int ch = 0; ch < 5; ++ch) a[o][ch] = 0.f;

        #pragma unroll
        for (int o = 0; o < 4; ++o) {
            #pragma unroll
            for (int t = 0; t < 11; ++t) {
                const float w = GW[t];
                a[o][0] += w * p [o + t];
                a[o][1] += w * q [o + t];
                a[o][2] += w * pp[o + t];
                a[o][3] += w * qq[o + t];
                a[o][4] += w * pq[o + t];
            }
        }
        #pragma unroll
        for (int ch = 0; ch < 5; ++ch) {
            float4 v = make_float4(a[0][ch], a[1][ch], a[2][ch], a[3][ch]);
            *(float4*)&Hb[ch][hr][c0] = v;
        }
    }
    __syncthreads();

    // ---- vertical pass: each thread 4 adjacent rows x 1 col, sliding reuse --
    const int vc  = tid & 31;
    const int vr0 = (tid >> 5) << 2;
    float acc[4][5];
    #pragma unroll
    for (int o = 0; o < 4; ++o)
        #pragma unroll
        for (int ch = 0; ch < 5; ++ch) acc[o][ch] = 0.f;

    const float* hb = &Hb[0][vr0][vc];
    #pragma unroll
    for (int j = 0; j < 15; ++j) {
        const float v0 = hb[j * HPITCH];
        const float v1 = hb[j * HPITCH + SH * HPITCH];
        const float v2 = hb[j * HPITCH + 2 * SH * HPITCH];
        const float v3 = hb[j * HPITCH + 3 * SH * HPITCH];
        const float v4 = hb[j * HPITCH + 4 * SH * HPITCH];
        #pragma unroll
        for (int o = 0; o < 4; ++o) {
            if (j - o >= 0 && j - o <= 10) {      // constant-folds per (j,o)
                const float w = GW[j - o];
                acc[o][0] += w * v0;
                acc[o][1] += w * v1;
                acc[o][2] += w * v2;
                acc[o][3] += w * v3;
                acc[o][4] += w * v4;
            }
        }
    }

    // ---- SSIM epilogue ----
    const float C1f = 1e-4f;
    const float C2f = 9e-4f;
    float lsum = 0.f;
    #pragma unroll
    for (int o = 0; o < 4; ++o) {
        float mu1 = acc[o][0], mu2 = acc[o][1];
        float m11 = acc[o][2], m22 = acc[o][3], m12 = acc[o][4];
        float mu1s = mu1 * mu1;
        float mu2s = mu2 * mu2;
        float mu12 = mu1 * mu2;
        float s1  = m11 - mu1s;
        float s2  = m22 - mu2s;
        float s12 = m12 - mu12;
        float num = (2.f * mu12 + C1f) * (2.f * s12 + C2f) * (s12 + 0.5f * C2f);
        float den = (mu1s + mu2s + C1f) * (s1 + s2 + C2f) * (sqrtf(s1 * s2) + 0.5f * C2f);
        lsum += num / den;
    }

    // ---- block reduction ----
    #pragma unroll
    for (int off = 32; off > 0; off >>= 1)
        lsum += __shfl_xor(lsum, off);
    const int wid  = tid >> 6;
    const int lane = tid & 63;
    if (lane == 0) wsum[wid] = lsum;
    __syncthreads();

    // ---- hierarchical atomic finish (single-kernel global mean) ----
    double* accd    = (double*)ws;                      // [32] slot sums
    unsigned* cnt   = (unsigned*)((char*)ws + 256);     // [32] slot counters
    unsigned* master = (unsigned*)((char*)ws + 384);    // 1 master counter

    if (tid == 0) {
        float s = wsum[0] + wsum[1] + wsum[2] + wsum[3];
        const int bid = (blockIdx.z * GY_ + blockIdx.y) * GX_ + blockIdx.x;
        const int slot = bid & (NSLOTS - 1);
        atomicAdd(&accd[slot], (double)s);
        __threadfence();
        unsigned old = atomicAdd(&cnt[slot], 1u);
        unsigned isLast = 0;
        if (old == PER_SLOT - 1) {
            unsigned old2 = atomicAdd(master, 1u);
            isLast = (old2 == NSLOTS - 1);
        }
        lastFlag = isLast;
    }
    __syncthreads();

    if (lastFlag && tid < 64) {
        __threadfence();
        double v = (tid < NSLOTS) ? atomicAdd(&accd[tid], 0.0) : 0.0;
        #pragma unroll
        for (int off = 32; off > 0; off >>= 1)
            v += __shfl_xor(v, off);
        if (tid == 0)
            out[0] = (float)(v * (1.0 / ((double)IMG_B * IMG_H * IMG_W)));
    }
}

extern "C" void kernel_launch(void* const* d_in, const int* in_sizes, int n_in,
                              void* d_out, int out_size, void* d_ws, size_t ws_size,
                              hipStream_t stream)
{
    const float* pred = (const float*)d_in[0];
    const float* yin  = (const float*)d_in[1];
    float* out = (float*)d_out;

    // zero the 32 double slots + 33 counters (ws is re-poisoned to 0xAA)
    hipMemsetAsync(d_ws, 0, 512, stream);

    dim3 grid(GX_, GY_, IMG_B);   // 24 x 24 x 32
    ssim_fused_kernel<<<grid, BLOCK, 0, stream>>>(pred, yin, out, d_ws);
}

// Round 3
// 299.506 us; speedup vs baseline: 2.1760x; 2.1760x over previous
//
#include <hip/hip_runtime.h>

#define TW 32
#define TH 32
#define SW 42          // TW + 10 halo
#define SH 42          // TH + 10 halo
#define SPITCH 44      // staged-tile pitch (mult of 4 -> 16B-aligned float4)
#define HPITCH 36      // h-filtered pitch (mult of 4; 36 mod 32 = 4 bank shift)
#define CHS (SH * HPITCH)  // channel stride in floats (1512)
#define BLOCK 256
#define IMG_W 768
#define IMG_H 768
#define IMG_B 32
#define GX_ (IMG_W / TW)
#define GY_ (IMG_H / TH)
#define NBLOCKS (GX_ * GY_ * IMG_B)   // 18432

// Gaussian window sigma=1.5, ws=11, normalized (f64-computed, f32-cast).
#define W0 0.00102838f
#define W1 0.00759876f
#define W2 0.03600077f
#define W3 0.10936069f
#define W4 0.21300554f
#define W5 0.26601173f

__global__ __launch_bounds__(BLOCK, 3) void ssim_tile_kernel(
    const float* __restrict__ pred, const float* __restrict__ yin,
    float* __restrict__ partial)
{
    constexpr float GW[11] = {W0, W1, W2, W3, W4, W5, W4, W3, W2, W1, W0};

    __shared__ __align__(16) float sp[SH * SPITCH];
    __shared__ __align__(16) float sy[SH * SPITCH];
    __shared__ __align__(16) float Hb[5][SH][HPITCH];
    __shared__ float wsum[BLOCK / 64];

    const int tid = threadIdx.x;
    const int x0 = blockIdx.x * TW;
    const int y0 = blockIdx.y * TH;
    const size_t base = (size_t)blockIdx.z * (size_t)(IMG_H * IMG_W);
    const float* pb = pred + base;
    const float* yb = yin + base;

    // ---- stage 42x42 halo'd tile (zero padding outside image) ----
    const bool interior = (x0 >= 5) && (x0 + TW + 5 <= IMG_W) &&
                          (y0 >= 5) && (y0 + TH + 5 <= IMG_H);
    {
        int r = tid / SW;
        int c = tid - r * SW;
        if (interior) {
            const float* pb2 = pb + (size_t)(y0 - 5) * IMG_W + (x0 - 5);
            const float* yb2 = yb + (size_t)(y0 - 5) * IMG_W + (x0 - 5);
            for (int it = tid; it < SH * SW; it += BLOCK) {
                int o = r * IMG_W + c;
                sp[r * SPITCH + c] = pb2[o];
                sy[r * SPITCH + c] = yb2[o];
                c += 4; r += 6;                  // 256 = 6*42 + 4
                if (c >= SW) { c -= SW; ++r; }
            }
        } else {
            for (int it = tid; it < SH * SW; it += BLOCK) {
                int gx = x0 + c - 5;
                int gy = y0 + r - 5;
                float vp = 0.f, vy = 0.f;
                if (gx >= 0 && gx < IMG_W && gy >= 0 && gy < IMG_H) {
                    size_t o = (size_t)gy * IMG_W + gx;
                    vp = pb[o];
                    vy = yb[o];
                }
                sp[r * SPITCH + c] = vp;
                sy[r * SPITCH + c] = vy;
                c += 4; r += 6;
                if (c >= SW) { c -= SW; ++r; }
            }
        }
    }
    __syncthreads();

    // ---- horizontal pass: 42 rows x 8 col-groups (4 outputs each) ----
    for (int it = tid; it < SH * 8; it += BLOCK) {
        const int hr = it >> 3;
        const int c0 = (it & 7) << 2;
        const float* rp = &sp[hr * SPITCH + c0];
        const float* ry = &sy[hr * SPITCH + c0];
        float p[14], q[14];
        *(float4*)(p)      = *(const float4*)(rp);
        *(float4*)(p + 4)  = *(const float4*)(rp + 4);
        *(float4*)(p + 8)  = *(const float4*)(rp + 8);
        *(float2*)(p + 12) = *(const float2*)(rp + 12);
        *(float4*)(q)      = *(const float4*)(ry);
        *(float4*)(q + 4)  = *(const float4*)(ry + 4);
        *(float4*)(q + 8)  = *(const float4*)(ry + 8);
        *(float2*)(q + 12) = *(const float2*)(ry + 12);

        float pp[14], qq[14], pq[14];
        #pragma unroll
        for (int k = 0; k < 14; ++k) {
            pp[k] = p[k] * p[k];
            qq[k] = q[k] * q[k];
            pq[k] = p[k] * q[k];
        }

        float a[4][5];
        #pragma unroll
        for (int o = 0; o < 4; ++o)
            #pragma unroll
            for (int ch = 0; ch < 5; ++ch) a[o][ch] = 0.f;

        #pragma unroll
        for (int o = 0; o < 4; ++o) {
            #pragma unroll
            for (int t = 0; t < 11; ++t) {
                const float w = GW[t];
                a[o][0] += w * p [o + t];
                a[o][1] += w * q [o + t];
                a[o][2] += w * pp[o + t];
                a[o][3] += w * qq[o + t];
                a[o][4] += w * pq[o + t];
            }
        }
        #pragma unroll
        for (int ch = 0; ch < 5; ++ch) {
            float4 v = make_float4(a[0][ch], a[1][ch], a[2][ch], a[3][ch]);
            *(float4*)&Hb[ch][hr][c0] = v;
        }
    }
    __syncthreads();

    // ---- vertical pass: thread = 4 adjacent rows x 1 col; batched loads ----
    const int vc  = tid & 31;
    const int vr0 = (tid >> 5) << 2;
    const float* hb = &Hb[0][vr0][vc];

    // load all 5 channels x 14 rows into registers first (70 outstanding
    // ds_reads -> latency hidden), then the pure-FMA sliding-window conv.
    float v[5][14];
    #pragma unroll
    for (int ch = 0; ch < 5; ++ch)
        #pragma unroll
        for (int j = 0; j < 14; ++j)
            v[ch][j] = hb[ch * CHS + j * HPITCH];

    float acc[4][5];
    #pragma unroll
    for (int o = 0; o < 4; ++o) {
        #pragma unroll
        for (int ch = 0; ch < 5; ++ch) {
            float a = 0.f;
            #pragma unroll
            for (int t = 0; t < 11; ++t)
                a += GW[t] * v[ch][o + t];
            acc[o][ch] = a;
        }
    }

    // ---- SSIM epilogue ----
    const float C1f = 1e-4f;
    const float C2f = 9e-4f;
    float lsum = 0.f;
    #pragma unroll
    for (int o = 0; o < 4; ++o) {
        float mu1 = acc[o][0], mu2 = acc[o][1];
        float m11 = acc[o][2], m22 = acc[o][3], m12 = acc[o][4];
        float mu1s = mu1 * mu1;
        float mu2s = mu2 * mu2;
        float mu12 = mu1 * mu2;
        float s1  = m11 - mu1s;
        float s2  = m22 - mu2s;
        float s12 = m12 - mu12;
        float num = (2.f * mu12 + C1f) * (2.f * s12 + C2f) * (s12 + 0.5f * C2f);
        float den = (mu1s + mu2s + C1f) * (s1 + s2 + C2f) * (sqrtf(s1 * s2) + 0.5f * C2f);
        lsum += num / den;
    }

    // ---- block reduction, plain store of the partial ----
    #pragma unroll
    for (int off = 32; off > 0; off >>= 1)
        lsum += __shfl_xor(lsum, off);
    const int wid  = tid >> 6;
    const int lane = tid & 63;
    if (lane == 0) wsum[wid] = lsum;
    __syncthreads();
    if (tid == 0) {
        const int bid = (blockIdx.z * GY_ + blockIdx.y) * GX_ + blockIdx.x;
        partial[bid] = wsum[0] + wsum[1] + wsum[2] + wsum[3];
    }
}

// ---------------------------------------------------------------------------
// Deterministic final reduction in double (fixed assignment + order).
// ---------------------------------------------------------------------------
__global__ __launch_bounds__(1024) void ssim_reduce_kernel(
    const float* __restrict__ partial, float* __restrict__ out)
{
    __shared__ double sd[1024];
    double s = 0.0;
    const float4* p4 = (const float4*)partial;      // NBLOCKS % 4 == 0
    for (int i = threadIdx.x; i < NBLOCKS / 4; i += 1024) {
        float4 v = p4[i];
        s += (double)v.x + (double)v.y + (double)v.z + (double)v.w;
    }
    sd[threadIdx.x] = s;
    __syncthreads();
    #pragma unroll
    for (int st = 512; st > 0; st >>= 1) {
        if (threadIdx.x < st) sd[threadIdx.x] += sd[threadIdx.x + st];
        __syncthreads();
    }
    if (threadIdx.x == 0)
        out[0] = (float)(sd[0] * (1.0 / ((double)IMG_B * IMG_H * IMG_W)));
}

extern "C" void kernel_launch(void* const* d_in, const int* in_sizes, int n_in,
                              void* d_out, int out_size, void* d_ws, size_t ws_size,
                              hipStream_t stream)
{
    const float* pred = (const float*)d_in[0];
    const float* yin  = (const float*)d_in[1];
    float* out     = (float*)d_out;
    float* partial = (float*)d_ws;

    dim3 grid(GX_, GY_, IMG_B);   // 24 x 24 x 32
    ssim_tile_kernel<<<grid, BLOCK, 0, stream>>>(pred, yin, partial);
    ssim_reduce_kernel<<<1, 1024, 0, stream>>>(partial, out);
}

// Round 4
// 247.818 us; speedup vs baseline: 2.6299x; 1.2086x over previous
//
#include <hip/hip_runtime.h>

#define TW 32
#define TH 32
#define SH 42              // TH + 10 halo rows
#define HPITCH 36          // h-filtered pitch (mult of 4; 36 mod 32 = 4 bank shift)
#define BLOCK 256
#define IMG_W 768
#define IMG_H 768
#define IMG_B 32
#define GX_ (IMG_W / TW)
#define GY_ (IMG_H / TH)
#define NBLOCKS (GX_ * GY_ * IMG_B)   // 18432

// Gaussian window sigma=1.5, ws=11, normalized (f64-computed, f32-cast).
#define W0 0.00102838f
#define W1 0.00759876f
#define W2 0.03600077f
#define W3 0.10936069f
#define W4 0.21300554f
#define W5 0.26601173f

__global__ __launch_bounds__(BLOCK, 5) void ssim_tile_kernel(
    const float* __restrict__ pred, const float* __restrict__ yin,
    float* __restrict__ partial)
{
    constexpr float GW[11] = {W0, W1, W2, W3, W4, W5, W4, W3, W2, W1, W0};

    __shared__ __align__(16) float Hb[5][SH][HPITCH];   // 30.2 KB
    __shared__ float wsum[BLOCK / 64];

    const int tid = threadIdx.x;
    const int x0 = blockIdx.x * TW;
    const int y0 = blockIdx.y * TH;
    const size_t base = (size_t)blockIdx.z * (size_t)(IMG_H * IMG_W);
    const float* pb = pred + base;
    const float* yb = yin + base;

    // fast path requires gy in-range for all halo rows and the 20-word
    // aligned x-window [x0-8, x0+TW+8) in-range.
    const bool interior = (x0 >= 8) && (x0 + TW + 8 <= IMG_W) &&
                          (y0 >= 5) && (y0 + TH + 5 <= IMG_H);

    // ---- horizontal pass: read halo rows DIRECTLY from global (L1/L2),
    //      42 rows x 8 col-groups (4 outputs each), channel-at-a-time ----
    for (int it = tid; it < SH * 8; it += BLOCK) {
        const int hr = it >> 3;
        const int c0 = (it & 7) << 2;
        const int gy = y0 + hr - 5;
        float p[14], q[14];

        if (interior) {
            // need words (x0+c0-5) .. (x0+c0+8); aligned base a0 = x0+c0-8,
            // so words a0+3 .. a0+16: scalar + 3x float4 + scalar.
            const float* rp = pb + (size_t)gy * IMG_W + (x0 + c0 - 8);
            const float* rq = yb + (size_t)gy * IMG_W + (x0 + c0 - 8);
            p[0] = rp[3];
            *(float4*)(p + 1) = *(const float4*)(rp + 4);
            *(float4*)(p + 5) = *(const float4*)(rp + 8);
            *(float4*)(p + 9) = *(const float4*)(rp + 12);
            p[13] = rp[16];
            q[0] = rq[3];
            *(float4*)(q + 1) = *(const float4*)(rq + 4);
            *(float4*)(q + 5) = *(const float4*)(rq + 8);
            *(float4*)(q + 9) = *(const float4*)(rq + 12);
            q[13] = rq[16];
        } else {
            if (gy >= 0 && gy < IMG_H) {
                const float* rowp = pb + (size_t)gy * IMG_W;
                const float* rowq = yb + (size_t)gy * IMG_W;
                #pragma unroll
                for (int k = 0; k < 14; ++k) {
                    const int gx = x0 + c0 - 5 + k;
                    const bool in = (gx >= 0) && (gx < IMG_W);
                    p[k] = in ? rowp[gx] : 0.f;   // exec-masked load, no OOB access
                    q[k] = in ? rowq[gx] : 0.f;
                }
            } else {
                #pragma unroll
                for (int k = 0; k < 14; ++k) { p[k] = 0.f; q[k] = 0.f; }
            }
        }

        // channel 0: p
        {
            float a0 = 0.f, a1 = 0.f, a2 = 0.f, a3 = 0.f;
            #pragma unroll
            for (int t = 0; t < 11; ++t) {
                const float w = GW[t];
                a0 += w * p[t]; a1 += w * p[t + 1];
                a2 += w * p[t + 2]; a3 += w * p[t + 3];
            }
            *(float4*)&Hb[0][hr][c0] = make_float4(a0, a1, a2, a3);
        }
        // channel 1: q
        {
            float a0 = 0.f, a1 = 0.f, a2 = 0.f, a3 = 0.f;
            #pragma unroll
            for (int t = 0; t < 11; ++t) {
                const float w = GW[t];
                a0 += w * q[t]; a1 += w * q[t + 1];
                a2 += w * q[t + 2]; a3 += w * q[t + 3];
            }
            *(float4*)&Hb[1][hr][c0] = make_float4(a0, a1, a2, a3);
        }
        // channel 2: p*p
        {
            float t14[14];
            #pragma unroll
            for (int k = 0; k < 14; ++k) t14[k] = p[k] * p[k];
            float a0 = 0.f, a1 = 0.f, a2 = 0.f, a3 = 0.f;
            #pragma unroll
            for (int t = 0; t < 11; ++t) {
                const float w = GW[t];
                a0 += w * t14[t]; a1 += w * t14[t + 1];
                a2 += w * t14[t + 2]; a3 += w * t14[t + 3];
            }
            *(float4*)&Hb[2][hr][c0] = make_float4(a0, a1, a2, a3);
        }
        // channel 3: q*q
        {
            float t14[14];
            #pragma unroll
            for (int k = 0; k < 14; ++k) t14[k] = q[k] * q[k];
            float a0 = 0.f, a1 = 0.f, a2 = 0.f, a3 = 0.f;
            #pragma unroll
            for (int t = 0; t < 11; ++t) {
                const float w = GW[t];
                a0 += w * t14[t]; a1 += w * t14[t + 1];
                a2 += w * t14[t + 2]; a3 += w * t14[t + 3];
            }
            *(float4*)&Hb[3][hr][c0] = make_float4(a0, a1, a2, a3);
        }
        // channel 4: p*q
        {
            float t14[14];
            #pragma unroll
            for (int k = 0; k < 14; ++k) t14[k] = p[k] * q[k];
            float a0 = 0.f, a1 = 0.f, a2 = 0.f, a3 = 0.f;
            #pragma unroll
            for (int t = 0; t < 11; ++t) {
                const float w = GW[t];
                a0 += w * t14[t]; a1 += w * t14[t + 1];
                a2 += w * t14[t + 2]; a3 += w * t14[t + 3];
            }
            *(float4*)&Hb[4][hr][c0] = make_float4(a0, a1, a2, a3);
        }
    }
    __syncthreads();

    // ---- vertical pass: thread = 4 adjacent rows x 1 col, channel-at-a-time
    //      (keeps live VGPRs low for 5 waves/SIMD) ----
    const int vc  = tid & 31;
    const int vr0 = (tid >> 5) << 2;
    float acc[5][4];
    #pragma unroll
    for (int ch = 0; ch < 5; ++ch) {
        const float* hb = &Hb[ch][vr0][vc];
        float v[14];
        #pragma unroll
        for (int j = 0; j < 14; ++j) v[j] = hb[j * HPITCH];
        #pragma unroll
        for (int o = 0; o < 4; ++o) {
            float a = 0.f;
            #pragma unroll
            for (int t = 0; t < 11; ++t)
                a += GW[t] * v[o + t];
            acc[ch][o] = a;
        }
    }

    // ---- SSIM epilogue ----
    const float C1f = 1e-4f;
    const float C2f = 9e-4f;
    float lsum = 0.f;
    #pragma unroll
    for (int o = 0; o < 4; ++o) {
        float mu1 = acc[0][o], mu2 = acc[1][o];
        float m11 = acc[2][o], m22 = acc[3][o], m12 = acc[4][o];
        float mu1s = mu1 * mu1;
        float mu2s = mu2 * mu2;
        float mu12 = mu1 * mu2;
        float s1  = m11 - mu1s;
        float s2  = m22 - mu2s;
        float s12 = m12 - mu12;
        float num = (2.f * mu12 + C1f) * (2.f * s12 + C2f) * (s12 + 0.5f * C2f);
        float den = (mu1s + mu2s + C1f) * (s1 + s2 + C2f) * (sqrtf(s1 * s2) + 0.5f * C2f);
        lsum += num / den;
    }

    // ---- block reduction, plain partial store ----
    #pragma unroll
    for (int off = 32; off > 0; off >>= 1)
        lsum += __shfl_xor(lsum, off);
    const int wid  = tid >> 6;
    const int lane = tid & 63;
    if (lane == 0) wsum[wid] = lsum;
    __syncthreads();
    if (tid == 0) {
        const int bid = (blockIdx.z * GY_ + blockIdx.y) * GX_ + blockIdx.x;
        partial[bid] = wsum[0] + wsum[1] + wsum[2] + wsum[3];
    }
}

// ---------------------------------------------------------------------------
// Deterministic final reduction in double (fixed assignment + order).
// ---------------------------------------------------------------------------
__global__ __launch_bounds__(1024) void ssim_reduce_kernel(
    const float* __restrict__ partial, float* __restrict__ out)
{
    __shared__ double sd[1024];
    double s = 0.0;
    const float4* p4 = (const float4*)partial;      // NBLOCKS % 4 == 0
    for (int i = threadIdx.x; i < NBLOCKS / 4; i += 1024) {
        float4 v = p4[i];
        s += (double)v.x + (double)v.y + (double)v.z + (double)v.w;
    }
    sd[threadIdx.x] = s;
    __syncthreads();
    #pragma unroll
    for (int st = 512; st > 0; st >>= 1) {
        if (threadIdx.x < st) sd[threadIdx.x] += sd[threadIdx.x + st];
        __syncthreads();
    }
    if (threadIdx.x == 0)
        out[0] = (float)(sd[0] * (1.0 / ((double)IMG_B * IMG_H * IMG_W)));
}

extern "C" void kernel_launch(void* const* d_in, const int* in_sizes, int n_in,
                              void* d_out, int out_size, void* d_ws, size_t ws_size,
                              hipStream_t stream)
{
    const float* pred = (const float*)d_in[0];
    const float* yin  = (const float*)d_in[1];
    float* out     = (float*)d_out;
    float* partial = (float*)d_ws;

    dim3 grid(GX_, GY_, IMG_B);   // 24 x 24 x 32
    ssim_tile_kernel<<<grid, BLOCK, 0, stream>>>(pred, yin, partial);
    ssim_reduce_kernel<<<1, 1024, 0, stream>>>(partial, out);
}